// Round 8
// baseline (743.437 us; speedup 1.0000x reference)
//
#include <hip/hip_runtime.h>
#include <hip/hip_bf16.h>
#include <stdint.h>

typedef __attribute__((ext_vector_type(4))) short short4v;
typedef __attribute__((ext_vector_type(8))) short short8v;
typedef __attribute__((ext_vector_type(4))) float float4v;

#define NN 8192
#define FIN 256
#define FOUT 256

__device__ __forceinline__ short f2bf(float f) {
    unsigned u = __float_as_uint(f);
    unsigned r = u + 0x7fffu + ((u >> 16) & 1u);   // RNE
    return (short)(r >> 16);
}

// W [256][256] fp32 -> WT [n][k] bf16
__global__ __launch_bounds__(256) void k_wt(const float* __restrict__ W, short* __restrict__ WT) {
    int k = blockIdx.x, n = threadIdx.x;
    WT[n * 256 + k] = f2bf(W[k * 256 + n]);
}

// Wh = h @ W  (M=8192, N=256, K=256), bf16 MFMA, 64x64 tile, BK=32
__global__ __launch_bounds__(256) void k_gemm1(const float* __restrict__ h, const short* __restrict__ WT,
                                               float* __restrict__ Wh) {
    __shared__ short sA[64 * 40];
    __shared__ short sB[64 * 40];
    int bm = blockIdx.x;   // 0..127
    int bn = blockIdx.y;   // 0..3
    int t  = threadIdx.x;
    int w = t >> 6, lane = t & 63, quad = lane >> 4, l16 = lane & 15;

    float4v acc[4];
#pragma unroll
    for (int c = 0; c < 4; c++)
#pragma unroll
        for (int j = 0; j < 4; j++) acc[c][j] = 0.f;

    int r  = t >> 2;            // 0..63
    int ko = (t & 3) * 8;       // 0,8,16,24

    for (int k0 = 0; k0 < 256; k0 += 32) {
        const float4v* src = (const float4v*)&h[(size_t)(64 * bm + r) * 256 + k0 + ko];
        float4v v0 = src[0], v1 = src[1];
        short8v pk;
        pk[0] = f2bf(v0[0]); pk[1] = f2bf(v0[1]); pk[2] = f2bf(v0[2]); pk[3] = f2bf(v0[3]);
        pk[4] = f2bf(v1[0]); pk[5] = f2bf(v1[1]); pk[6] = f2bf(v1[2]); pk[7] = f2bf(v1[3]);
        *(short8v*)&sA[r * 40 + ko] = pk;
        short8v bv = *(const short8v*)&WT[(size_t)(64 * bn + r) * 256 + k0 + ko];
        *(short8v*)&sB[r * 40 + ko] = bv;
        __syncthreads();

        short8v af = *(const short8v*)&sA[(16 * w + l16) * 40 + quad * 8];
#pragma unroll
        for (int c = 0; c < 4; c++) {
            short8v bf = *(const short8v*)&sB[(16 * c + l16) * 40 + quad * 8];
            acc[c] = __builtin_amdgcn_mfma_f32_16x16x32_bf16(af, bf, acc[c], 0, 0, 0);
        }
        __syncthreads();
    }
#pragma unroll
    for (int c = 0; c < 4; c++)
#pragma unroll
        for (int j = 0; j < 4; j++) {
            int row = 64 * bm + 16 * w + quad * 4 + j;
            int col = 64 * bn + 16 * c + l16;
            Wh[(size_t)row * 256 + col] = acc[c][j];
        }
}

// Wh1 = Wh@a1, Wh2 = Wh@a2, global max(Wh2) via encoded atomicMax. 4 rows/block (1/wave).
__global__ __launch_bounds__(256) void k_rowstats(const float* __restrict__ Wh, const float* __restrict__ a,
                                                  float* __restrict__ Wh1, float* __restrict__ Wh2,
                                                  unsigned* __restrict__ maxenc) {
    int w = threadIdx.x >> 6, lane = threadIdx.x & 63;
    int row = blockIdx.x * 4 + w;
    float s1 = 0.f, s2 = 0.f;
#pragma unroll
    for (int j = 0; j < 4; j++) {
        int c = lane + 64 * j;
        float v = Wh[(size_t)row * 256 + c];
        s1 += v * a[c];
        s2 += v * a[256 + c];
    }
#pragma unroll
    for (int off = 32; off; off >>= 1) {
        s1 += __shfl_down(s1, off);
        s2 += __shfl_down(s2, off);
    }
    if (lane == 0) {
        Wh1[row] = s1;
        Wh2[row] = s2;
        unsigned u = __float_as_uint(s2);
        unsigned key = (u & 0x80000000u) ? ~u : (u | 0x80000000u);
        atomicMax(maxenc, key);
    }
}

// WhT[n][k] bf16 from Wh[k][n] fp32, 64x64 LDS tile
__global__ __launch_bounds__(256) void k_transpose(const float* __restrict__ Wh, short* __restrict__ WhT) {
    __shared__ short sT[64 * 72];
    int bm = blockIdx.x, bn = blockIdx.y;
    int t = threadIdx.x;
#pragma unroll
    for (int i = 0; i < 4; i++) {
        int idx = i * 256 + t;
        int r = idx >> 4, c4 = (idx & 15) * 4;
        float4v v = *(const float4v*)&Wh[(size_t)(64 * bm + r) * 256 + 64 * bn + c4];
#pragma unroll
        for (int j = 0; j < 4; j++) sT[(c4 + j) * 72 + r] = f2bf(v[j]);
    }
    __syncthreads();
    int c = t >> 2, ro = (t & 3) * 16;
#pragma unroll
    for (int hh = 0; hh < 2; hh++) {
        short8v v = *(const short8v*)&sT[c * 72 + ro + 8 * hh];
        *(short8v*)&WhT[(size_t)(64 * bn + c) * 8192 + 64 * bm + ro + 8 * hh] = v;
    }
}

// Fused masked-softmax GEMM — BARRIER-FREE, LDS-FREE, wave-independent.
// Each wave: M=32 rows (2 A-frags), N=128 cols (8 B-frags), K-slice Ksub.
// A (P matrix) computed directly in MFMA A-fragment layout from adj + rank-1 scores.
// B-frags read from L2-resident WhT via plain global loads (compiler vmcnt pipelining).
// gw decode: ng = gw&1 (the 2 n-group waves of one m-tile share a block -> L1 adj reuse),
// mtile = (gw>>1)&255, sidx = gw>>9.
__global__ __launch_bounds__(256, 2) void k_gat(const float* __restrict__ adj,
                                                const short* __restrict__ WhT,
                                                const float* __restrict__ Wh1, const float* __restrict__ Wh2,
                                                const unsigned* __restrict__ maxenc,
                                                float* __restrict__ Cpart, float* __restrict__ Lpart,
                                                int Ksub) {
    int t = threadIdx.x;
    int lane = t & 63, l16 = lane & 15, quad = lane >> 4;
    int gw = blockIdx.x * 4 + (t >> 6);
    int ng    = gw & 1;
    int mtile = (gw >> 1) & 255;
    int sidx  = gw >> 9;
    int kb = sidx * Ksub;
    int m0 = mtile * 32;
    int n0 = ng * 128;

    // decode global max(Wh2)
    unsigned key = maxenc[0];
    unsigned u = (key & 0x80000000u) ? (key & 0x7fffffffu) : ~key;
    float maxw2 = __uint_as_float(u);

    float wh1r[2], ci[2];
#pragma unroll
    for (int rr = 0; rr < 2; rr++) {
        wh1r[rr] = Wh1[m0 + rr * 16 + l16];
        float sup = wh1r[rr] + maxw2;
        ci[rr] = fmaxf(sup, 0.2f * sup);
    }

    const float* adj0 = &adj[(size_t)(m0 + l16) * 8192 + kb + quad * 8];
    const float* adj1 = adj0 + (size_t)16 * 8192;
    const float* w2p  = &Wh2[kb + quad * 8];
    const short* bp   = &WhT[(size_t)(n0 + l16) * 8192 + kb + quad * 8];

    float4v acc[2][8];
#pragma unroll
    for (int rr = 0; rr < 2; rr++)
#pragma unroll
        for (int c = 0; c < 8; c++)
#pragma unroll
            for (int j = 0; j < 4; j++) acc[rr][c][j] = 0.f;
    float lsum0 = 0.f, lsum1 = 0.f;

    for (int k0 = 0; k0 < Ksub; k0 += 32) {
        // ---- all loads for this iter (independent; compiler pipelines with vmcnt(N))
        float4v a0a = *(const float4v*)(adj0 + k0);
        float4v a0b = *(const float4v*)(adj0 + k0 + 4);
        float4v a1a = *(const float4v*)(adj1 + k0);
        float4v a1b = *(const float4v*)(adj1 + k0 + 4);
        float4v w2a = *(const float4v*)(w2p + k0);
        float4v w2b = *(const float4v*)(w2p + k0 + 4);
        short8v bf[8];
#pragma unroll
        for (int c = 0; c < 8; c++)
            bf[c] = *(const short8v*)(bp + c * 16 * 8192 + k0);

        // ---- P fragments in A-layout: af[rr][j], j = quad*8+j k-position
        short8v af0, af1;
#pragma unroll
        for (int j = 0; j < 8; j++) {
            float w2v = (j < 4) ? w2a[j] : w2b[j - 4];
            float aj0 = (j < 4) ? a0a[j] : a0b[j - 4];
            float aj1 = (j < 4) ? a1a[j] : a1b[j - 4];
            float s0 = wh1r[0] + w2v;
            float s1 = wh1r[1] + w2v;
            float f0 = fmaxf(s0, 0.2f * s0);
            float f1 = fmaxf(s1, 0.2f * s1);
            float p0 = __expf(f0 - ci[0]);
            float p1 = __expf(f1 - ci[1]);
            p0 = (aj0 > 0.f) ? p0 : 0.f;
            p1 = (aj1 > 0.f) ? p1 : 0.f;
            lsum0 += p0;
            lsum1 += p1;
            af0[j] = f2bf(p0);
            af1[j] = f2bf(p1);
        }

        // ---- MFMA: 16 per iter, no barriers anywhere
#pragma unroll
        for (int c = 0; c < 8; c++) {
            acc[0][c] = __builtin_amdgcn_mfma_f32_16x16x32_bf16(af0, bf[c], acc[0][c], 0, 0, 0);
            acc[1][c] = __builtin_amdgcn_mfma_f32_16x16x32_bf16(af1, bf[c], acc[1][c], 0, 0, 0);
        }
    }

    // row sums: reduce across the 4 quads (lanes l16, l16+16, l16+32, l16+48)
    lsum0 += __shfl_xor(lsum0, 16);
    lsum0 += __shfl_xor(lsum0, 32);
    lsum1 += __shfl_xor(lsum1, 16);
    lsum1 += __shfl_xor(lsum1, 32);
    if (ng == 0 && quad == 0) {
        Lpart[(size_t)sidx * NN + m0 + l16]      = lsum0;
        Lpart[(size_t)sidx * NN + m0 + 16 + l16] = lsum1;
    }

    // C/D layout: col = l16, row(local) = quad*4 + j
#pragma unroll
    for (int rr = 0; rr < 2; rr++)
#pragma unroll
        for (int c = 0; c < 8; c++)
#pragma unroll
            for (int j = 0; j < 4; j++) {
                int row = m0 + rr * 16 + quad * 4 + j;
                int col = n0 + c * 16 + l16;
                Cpart[((size_t)sidx * NN + row) * 256 + col] = acc[rr][c][j];
            }
}

// out = elu( (sum_s Cpart[s]) / (sum_s Lpart[s]) )
__global__ __launch_bounds__(256) void k_final(const float* __restrict__ Cpart, const float* __restrict__ Lpart,
                                               float* __restrict__ out, int S) {
    int idx = blockIdx.x * 256 + threadIdx.x;     // one float4 per thread; 2048 blocks
    int row = idx >> 6;
    int c4 = (idx & 63) * 4;
    float4v sum;
    sum[0] = sum[1] = sum[2] = sum[3] = 0.f;
    float l = 0.f;
    for (int s = 0; s < S; s++) {
        float4v v = *(const float4v*)&Cpart[((size_t)s * NN + row) * 256 + c4];
#pragma unroll
        for (int j = 0; j < 4; j++) sum[j] += v[j];
        l += Lpart[(size_t)s * NN + row];
    }
    float inv = 1.0f / fmaxf(l, 1e-30f);
    float4v o;
#pragma unroll
    for (int j = 0; j < 4; j++) {
        float x = sum[j] * inv;
        o[j] = (x > 0.f) ? x : (__expf(x) - 1.f);
    }
    *(float4v*)&out[(size_t)row * 256 + c4] = o;
}

extern "C" void kernel_launch(void* const* d_in, const int* in_sizes, int n_in,
                              void* d_out, int out_size, void* d_ws, size_t ws_size,
                              hipStream_t stream) {
    const float* h   = (const float*)d_in[0];
    const float* adj = (const float*)d_in[1];
    const float* W   = (const float*)d_in[2];
    const float* a   = (const float*)d_in[3];
    float* out = (float*)d_out;

    int S = 4;
    if ((size_t)(12 * 1024 * 1024) + (size_t)S * 8 * 1024 * 1024 + (2 << 20) > ws_size) S = 2;
    int Ksub = NN / S;

    // ws layout (~45 MB at S=4):
    //  [0, 8MB)        Wh (fp32)
    //  [8MB, 12MB)     WhT (bf16)
    //  [12MB, 12+S*8)  Cpart (fp32, S slices)
    //  tail: WT 128KB | Wh1 32KB | Wh2 32KB | Lpart S*32KB | maxenc
    char* ws = (char*)d_ws;
    float*    Wh     = (float*)(ws);
    short*    WhT    = (short*)(ws + 8388608);
    float*    Cpart  = (float*)(ws + 12582912);
    char*     tail   = ws + 12582912 + (size_t)S * 8388608;
    short*    WT     = (short*)(tail);
    float*    Wh1    = (float*)(tail + 131072);
    float*    Wh2    = (float*)(tail + 163840);
    float*    Lpart  = (float*)(tail + 196608);
    unsigned* maxenc = (unsigned*)(tail + 196608 + S * 32768);

    hipMemsetAsync(maxenc, 0, sizeof(unsigned), stream);

    k_wt<<<256, 256, 0, stream>>>(W, WT);
    k_gemm1<<<dim3(128, 4), 256, 0, stream>>>(h, WT, Wh);
    k_rowstats<<<2048, 256, 0, stream>>>(Wh, a, Wh1, Wh2, maxenc);
    k_transpose<<<dim3(128, 4), 256, 0, stream>>>(Wh, WhT);
    // total waves = 256 mtiles * 2 ng * S ; 4 waves/block
    k_gat<<<128 * S, 256, 0, stream>>>(adj, WhT, Wh1, Wh2, maxenc, Cpart, Lpart, Ksub);
    k_final<<<2048, 256, 0, stream>>>(Cpart, Lpart, out, S);
}

// Round 9
// 696.850 us; speedup vs baseline: 1.0669x; 1.0669x over previous
//
#include <hip/hip_runtime.h>
#include <hip/hip_bf16.h>
#include <stdint.h>

typedef __attribute__((ext_vector_type(4))) short short4v;
typedef __attribute__((ext_vector_type(8))) short short8v;
typedef __attribute__((ext_vector_type(4))) float float4v;

#define NN 8192
#define FIN 256
#define FOUT 256

__device__ __forceinline__ short f2bf(float f) {
    unsigned u = __float_as_uint(f);
    unsigned r = u + 0x7fffu + ((u >> 16) & 1u);   // RNE
    return (short)(r >> 16);
}

// W [256][256] fp32 -> WT [n][k] bf16
__global__ __launch_bounds__(256) void k_wt(const float* __restrict__ W, short* __restrict__ WT) {
    int k = blockIdx.x, n = threadIdx.x;
    WT[n * 256 + k] = f2bf(W[k * 256 + n]);
}

// Wh = h @ W  (M=8192, N=256, K=256), bf16 MFMA, 64x64 tile, BK=32
__global__ __launch_bounds__(256) void k_gemm1(const float* __restrict__ h, const short* __restrict__ WT,
                                               float* __restrict__ Wh) {
    __shared__ short sA[64 * 40];
    __shared__ short sB[64 * 40];
    int bm = blockIdx.x;   // 0..127
    int bn = blockIdx.y;   // 0..3
    int t  = threadIdx.x;
    int w = t >> 6, lane = t & 63, quad = lane >> 4, l16 = lane & 15;

    float4v acc[4];
#pragma unroll
    for (int c = 0; c < 4; c++)
#pragma unroll
        for (int j = 0; j < 4; j++) acc[c][j] = 0.f;

    int r  = t >> 2;            // 0..63
    int ko = (t & 3) * 8;       // 0,8,16,24

    for (int k0 = 0; k0 < 256; k0 += 32) {
        const float4v* src = (const float4v*)&h[(size_t)(64 * bm + r) * 256 + k0 + ko];
        float4v v0 = src[0], v1 = src[1];
        short8v pk;
        pk[0] = f2bf(v0[0]); pk[1] = f2bf(v0[1]); pk[2] = f2bf(v0[2]); pk[3] = f2bf(v0[3]);
        pk[4] = f2bf(v1[0]); pk[5] = f2bf(v1[1]); pk[6] = f2bf(v1[2]); pk[7] = f2bf(v1[3]);
        *(short8v*)&sA[r * 40 + ko] = pk;
        short8v bv = *(const short8v*)&WT[(size_t)(64 * bn + r) * 256 + k0 + ko];
        *(short8v*)&sB[r * 40 + ko] = bv;
        __syncthreads();

        short8v af = *(const short8v*)&sA[(16 * w + l16) * 40 + quad * 8];
#pragma unroll
        for (int c = 0; c < 4; c++) {
            short8v bf = *(const short8v*)&sB[(16 * c + l16) * 40 + quad * 8];
            acc[c] = __builtin_amdgcn_mfma_f32_16x16x32_bf16(af, bf, acc[c], 0, 0, 0);
        }
        __syncthreads();
    }
#pragma unroll
    for (int c = 0; c < 4; c++)
#pragma unroll
        for (int j = 0; j < 4; j++) {
            int row = 64 * bm + 16 * w + quad * 4 + j;
            int col = 64 * bn + 16 * c + l16;
            Wh[(size_t)row * 256 + col] = acc[c][j];
        }
}

// Wh1 = Wh@a1, Wh2 = Wh@a2, global max(Wh2) via encoded atomicMax. 4 rows/block (1/wave).
__global__ __launch_bounds__(256) void k_rowstats(const float* __restrict__ Wh, const float* __restrict__ a,
                                                  float* __restrict__ Wh1, float* __restrict__ Wh2,
                                                  unsigned* __restrict__ maxenc) {
    int w = threadIdx.x >> 6, lane = threadIdx.x & 63;
    int row = blockIdx.x * 4 + w;
    float s1 = 0.f, s2 = 0.f;
#pragma unroll
    for (int j = 0; j < 4; j++) {
        int c = lane + 64 * j;
        float v = Wh[(size_t)row * 256 + c];
        s1 += v * a[c];
        s2 += v * a[256 + c];
    }
#pragma unroll
    for (int off = 32; off; off >>= 1) {
        s1 += __shfl_down(s1, off);
        s2 += __shfl_down(s2, off);
    }
    if (lane == 0) {
        Wh1[row] = s1;
        Wh2[row] = s2;
        unsigned u = __float_as_uint(s2);
        unsigned key = (u & 0x80000000u) ? ~u : (u | 0x80000000u);
        atomicMax(maxenc, key);
    }
}

// WhT[n][k] bf16 from Wh[k][n] fp32, 64x64 LDS tile
__global__ __launch_bounds__(256) void k_transpose(const float* __restrict__ Wh, short* __restrict__ WhT) {
    __shared__ short sT[64 * 72];
    int bm = blockIdx.x, bn = blockIdx.y;
    int t = threadIdx.x;
#pragma unroll
    for (int i = 0; i < 4; i++) {
        int idx = i * 256 + t;
        int r = idx >> 4, c4 = (idx & 15) * 4;
        float4v v = *(const float4v*)&Wh[(size_t)(64 * bm + r) * 256 + 64 * bn + c4];
#pragma unroll
        for (int j = 0; j < 4; j++) sT[(c4 + j) * 72 + r] = f2bf(v[j]);
    }
    __syncthreads();
    int c = t >> 2, ro = (t & 3) * 16;
#pragma unroll
    for (int hh = 0; hh < 2; hh++) {
        short8v v = *(const short8v*)&sT[c * 72 + ro + 8 * hh];
        *(short8v*)&WhT[(size_t)(64 * bn + c) * 8192 + 64 * bm + ro + 8 * hh] = v;
    }
}

// Fused masked-softmax GEMM. Grid (128, S). Block 512 thr / 8 waves.
// Block: M=64 (2 m-tiles), N=256 (4 n-groups), K-slice Ksub; wave = (ng, mt) unit.
// P computed IN REGISTERS in MFMA A-frag layout (no sA, no A-barrier).
// B double-buffered in LDS in FRAGMENT ORDER (conflict-free ds_read_b128);
// staged global->reg at chunk start, reg->LDS at chunk end: ONE barrier per
// 64-wide K chunk, and the vmcnt drain at the barrier hits loads issued a
// full chunk earlier (already arrived) — no convoy.
__global__ __launch_bounds__(512, 4) void k_gat(const float* __restrict__ adj,
                                                const short* __restrict__ WhT,
                                                const float* __restrict__ Wh1, const float* __restrict__ Wh2,
                                                const unsigned* __restrict__ maxenc,
                                                float* __restrict__ Cpart, float* __restrict__ Lpart,
                                                int Ksub) {
    __shared__ short sB[2][16384];   // 2 x 32 KB, fragment order: ((cg*2+kk)*64+lane)*8
    int bm = blockIdx.x;
    int sidx = blockIdx.y;
    int kb = sidx * Ksub;
    int t = threadIdx.x;
    int lane = t & 63, l16 = lane & 15, quad = lane >> 4;
    int w = t >> 6;                  // 0..7
    int ng = w & 3;                  // n-group: cols ng*64..+63
    int mt = w >> 2;                 // m-tile: rows bm*64 + mt*32..+31
    int m0 = bm * 64 + mt * 32;
    int n0 = ng * 64;

    // decode global max(Wh2)
    unsigned key = maxenc[0];
    unsigned uu = (key & 0x80000000u) ? (key & 0x7fffffffu) : ~key;
    float maxw2 = __uint_as_float(uu);

    float wh1r[2], ci[2];
#pragma unroll
    for (int rr = 0; rr < 2; rr++) {
        wh1r[rr] = Wh1[m0 + rr * 16 + l16];
        float sup = wh1r[rr] + maxw2;
        ci[rr] = fmaxf(sup, 0.2f * sup);
    }

    const float* adjp0 = &adj[(size_t)(m0 + l16) * 8192 + kb + quad * 8];
    const float* adjp1 = adjp0 + (size_t)16 * 8192;
    const float* w2p   = &Wh2[kb + quad * 8];

    // staging: thread t stages 4 16-B chunks; chunk s=i*512+t -> unit=s>>6, lane
    // unit = cg*2+kks; src = WhT[cg*16+l16][kb + kks*32 + quad*8 + ch*64 ...]
    const short* srcp[4];
#pragma unroll
    for (int i = 0; i < 4; i++) {
        int unit = i * 8 + w;
        int cg = unit >> 1, kks = unit & 1;
        srcp[i] = &WhT[(size_t)(cg * 16 + l16) * 8192 + kb + kks * 32 + quad * 8];
    }

    float4v acc[2][4];
#pragma unroll
    for (int rr = 0; rr < 2; rr++)
#pragma unroll
        for (int c = 0; c < 4; c++)
#pragma unroll
            for (int j = 0; j < 4; j++) acc[rr][c][j] = 0.f;
    float lsum0 = 0.f, lsum1 = 0.f;

    // stage chunk 0
    short8v sr[4];
#pragma unroll
    for (int i = 0; i < 4; i++) sr[i] = *(const short8v*)(srcp[i]);
#pragma unroll
    for (int i = 0; i < 4; i++) *(short8v*)&sB[0][((i * 512 + t)) * 8] = sr[i];
    __syncthreads();

    int nch = Ksub >> 6;
    for (int ch = 0; ch < nch; ch++) {
        int cur = ch & 1;
        // issue next chunk's staging loads NOW (drain at barrier is free)
        if (ch + 1 < nch) {
#pragma unroll
            for (int i = 0; i < 4; i++) sr[i] = *(const short8v*)(srcp[i] + (ch + 1) * 64);
        }
        int kg = ch * 64;
#pragma unroll
        for (int kk = 0; kk < 2; kk++) {
            int ko = kg + kk * 32;
            float4v a0a = *(const float4v*)(adjp0 + ko);
            float4v a0b = *(const float4v*)(adjp0 + ko + 4);
            float4v a1a = *(const float4v*)(adjp1 + ko);
            float4v a1b = *(const float4v*)(adjp1 + ko + 4);
            float4v w2a = *(const float4v*)(w2p + ko);
            float4v w2b = *(const float4v*)(w2p + ko + 4);
            short8v af0, af1;
#pragma unroll
            for (int j = 0; j < 8; j++) {
                float w2v = (j < 4) ? w2a[j] : w2b[j - 4];
                float aj0 = (j < 4) ? a0a[j] : a0b[j - 4];
                float aj1 = (j < 4) ? a1a[j] : a1b[j - 4];
                float s0 = wh1r[0] + w2v;
                float s1 = wh1r[1] + w2v;
                float f0 = fmaxf(s0, 0.2f * s0);
                float f1 = fmaxf(s1, 0.2f * s1);
                float p0 = __expf(f0 - ci[0]) * aj0;   // adj is exactly 0.0/1.0
                float p1 = __expf(f1 - ci[1]) * aj1;
                lsum0 += p0;
                lsum1 += p1;
                af0[j] = f2bf(p0);
                af1[j] = f2bf(p1);
            }
#pragma unroll
            for (int c = 0; c < 4; c++) {
                short8v bf = *(const short8v*)&sB[cur][(((ng * 4 + c) * 2 + kk) * 64 + lane) * 8];
                acc[0][c] = __builtin_amdgcn_mfma_f32_16x16x32_bf16(af0, bf, acc[0][c], 0, 0, 0);
                acc[1][c] = __builtin_amdgcn_mfma_f32_16x16x32_bf16(af1, bf, acc[1][c], 0, 0, 0);
            }
        }
        if (ch + 1 < nch) {
            int nxt = cur ^ 1;
#pragma unroll
            for (int i = 0; i < 4; i++) *(short8v*)&sB[nxt][((i * 512 + t)) * 8] = sr[i];
        }
        __syncthreads();
    }

    // row sums: reduce across the 4 quads
    lsum0 += __shfl_xor(lsum0, 16);
    lsum0 += __shfl_xor(lsum0, 32);
    lsum1 += __shfl_xor(lsum1, 16);
    lsum1 += __shfl_xor(lsum1, 32);
    if (ng == 0 && quad == 0) {
        Lpart[(size_t)sidx * NN + m0 + l16]      = lsum0;
        Lpart[(size_t)sidx * NN + m0 + 16 + l16] = lsum1;
    }

    // C/D layout: col = l16, row(local) = quad*4 + j
#pragma unroll
    for (int rr = 0; rr < 2; rr++)
#pragma unroll
        for (int c = 0; c < 4; c++)
#pragma unroll
            for (int j = 0; j < 4; j++) {
                int row = m0 + rr * 16 + quad * 4 + j;
                int col = n0 + c * 16 + l16;
                Cpart[((size_t)sidx * NN + row) * 256 + col] = acc[rr][c][j];
            }
}

// out = elu( (sum_s Cpart[s]) / (sum_s Lpart[s]) )
__global__ __launch_bounds__(256) void k_final(const float* __restrict__ Cpart, const float* __restrict__ Lpart,
                                               float* __restrict__ out, int S) {
    int idx = blockIdx.x * 256 + threadIdx.x;     // one float4 per thread; 2048 blocks
    int row = idx >> 6;
    int c4 = (idx & 63) * 4;
    float4v sum;
    sum[0] = sum[1] = sum[2] = sum[3] = 0.f;
    float l = 0.f;
    for (int s = 0; s < S; s++) {
        float4v v = *(const float4v*)&Cpart[((size_t)s * NN + row) * 256 + c4];
#pragma unroll
        for (int j = 0; j < 4; j++) sum[j] += v[j];
        l += Lpart[(size_t)s * NN + row];
    }
    float inv = 1.0f / fmaxf(l, 1e-30f);
    float4v o;
#pragma unroll
    for (int j = 0; j < 4; j++) {
        float x = sum[j] * inv;
        o[j] = (x > 0.f) ? x : (__expf(x) - 1.f);
    }
    *(float4v*)&out[(size_t)row * 256 + c4] = o;
}

extern "C" void kernel_launch(void* const* d_in, const int* in_sizes, int n_in,
                              void* d_out, int out_size, void* d_ws, size_t ws_size,
                              hipStream_t stream) {
    const float* h   = (const float*)d_in[0];
    const float* adj = (const float*)d_in[1];
    const float* W   = (const float*)d_in[2];
    const float* a   = (const float*)d_in[3];
    float* out = (float*)d_out;

    int S = 4;
    if ((size_t)(12 * 1024 * 1024) + (size_t)S * 8 * 1024 * 1024 + (2 << 20) > ws_size) S = 2;
    int Ksub = NN / S;

    // ws layout (~45 MB at S=4):
    //  [0, 8MB)        Wh (fp32)
    //  [8MB, 12MB)     WhT (bf16)
    //  [12MB, 12+S*8)  Cpart (fp32, S slices)
    //  tail: WT 128KB | Wh1 32KB | Wh2 32KB | Lpart S*32KB | maxenc
    char* ws = (char*)d_ws;
    float*    Wh     = (float*)(ws);
    short*    WhT    = (short*)(ws + 8388608);
    float*    Cpart  = (float*)(ws + 12582912);
    char*     tail   = ws + 12582912 + (size_t)S * 8388608;
    short*    WT     = (short*)(tail);
    float*    Wh1    = (float*)(tail + 131072);
    float*    Wh2    = (float*)(tail + 163840);
    float*    Lpart  = (float*)(tail + 196608);
    unsigned* maxenc = (unsigned*)(tail + 196608 + S * 32768);

    hipMemsetAsync(maxenc, 0, sizeof(unsigned), stream);

    k_wt<<<256, 256, 0, stream>>>(W, WT);
    k_gemm1<<<dim3(128, 4), 256, 0, stream>>>(h, WT, Wh);
    k_rowstats<<<2048, 256, 0, stream>>>(Wh, a, Wh1, Wh2, maxenc);
    k_transpose<<<dim3(128, 4), 256, 0, stream>>>(Wh, WhT);
    k_gat<<<dim3(128, S), 512, 0, stream>>>(adj, WhT, Wh1, Wh2, maxenc, Cpart, Lpart, Ksub);
    k_final<<<2048, 256, 0, stream>>>(Cpart, Lpart, out, S);
}

// Round 10
// 579.293 us; speedup vs baseline: 1.2834x; 1.2029x over previous
//
#include <hip/hip_runtime.h>
#include <hip/hip_bf16.h>
#include <stdint.h>

typedef __attribute__((ext_vector_type(4))) short short4v;
typedef __attribute__((ext_vector_type(8))) short short8v;
typedef __attribute__((ext_vector_type(4))) float float4v;

#define NN 8192
#define FIN 256
#define FOUT 256

__device__ __forceinline__ short f2bf(float f) {
    unsigned u = __float_as_uint(f);
    unsigned r = u + 0x7fffu + ((u >> 16) & 1u);   // RNE
    return (short)(r >> 16);
}

// W [256][256] fp32 -> WT [n][k] bf16
__global__ __launch_bounds__(256) void k_wt(const float* __restrict__ W, short* __restrict__ WT) {
    int k = blockIdx.x, n = threadIdx.x;
    WT[n * 256 + k] = f2bf(W[k * 256 + n]);
}

// Wh = h @ W  (M=8192, N=256, K=256), bf16 MFMA, 64x64 tile, BK=32
__global__ __launch_bounds__(256) void k_gemm1(const float* __restrict__ h, const short* __restrict__ WT,
                                               float* __restrict__ Wh) {
    __shared__ short sA[64 * 40];
    __shared__ short sB[64 * 40];
    int bm = blockIdx.x;   // 0..127
    int bn = blockIdx.y;   // 0..3
    int t  = threadIdx.x;
    int w = t >> 6, lane = t & 63, quad = lane >> 4, l16 = lane & 15;

    float4v acc[4];
#pragma unroll
    for (int c = 0; c < 4; c++)
#pragma unroll
        for (int j = 0; j < 4; j++) acc[c][j] = 0.f;

    int r  = t >> 2;            // 0..63
    int ko = (t & 3) * 8;       // 0,8,16,24

    for (int k0 = 0; k0 < 256; k0 += 32) {
        const float4v* src = (const float4v*)&h[(size_t)(64 * bm + r) * 256 + k0 + ko];
        float4v v0 = src[0], v1 = src[1];
        short8v pk;
        pk[0] = f2bf(v0[0]); pk[1] = f2bf(v0[1]); pk[2] = f2bf(v0[2]); pk[3] = f2bf(v0[3]);
        pk[4] = f2bf(v1[0]); pk[5] = f2bf(v1[1]); pk[6] = f2bf(v1[2]); pk[7] = f2bf(v1[3]);
        *(short8v*)&sA[r * 40 + ko] = pk;
        short8v bv = *(const short8v*)&WT[(size_t)(64 * bn + r) * 256 + k0 + ko];
        *(short8v*)&sB[r * 40 + ko] = bv;
        __syncthreads();

        short8v af = *(const short8v*)&sA[(16 * w + l16) * 40 + quad * 8];
#pragma unroll
        for (int c = 0; c < 4; c++) {
            short8v bf = *(const short8v*)&sB[(16 * c + l16) * 40 + quad * 8];
            acc[c] = __builtin_amdgcn_mfma_f32_16x16x32_bf16(af, bf, acc[c], 0, 0, 0);
        }
        __syncthreads();
    }
#pragma unroll
    for (int c = 0; c < 4; c++)
#pragma unroll
        for (int j = 0; j < 4; j++) {
            int row = 64 * bm + 16 * w + quad * 4 + j;
            int col = 64 * bn + 16 * c + l16;
            Wh[(size_t)row * 256 + col] = acc[c][j];
        }
}

// Wh1 = Wh@a1, Wh2 = Wh@a2, global max(Wh2) via encoded atomicMax. 4 rows/block (1/wave).
__global__ __launch_bounds__(256) void k_rowstats(const float* __restrict__ Wh, const float* __restrict__ a,
                                                  float* __restrict__ Wh1, float* __restrict__ Wh2,
                                                  unsigned* __restrict__ maxenc) {
    int w = threadIdx.x >> 6, lane = threadIdx.x & 63;
    int row = blockIdx.x * 4 + w;
    float s1 = 0.f, s2 = 0.f;
#pragma unroll
    for (int j = 0; j < 4; j++) {
        int c = lane + 64 * j;
        float v = Wh[(size_t)row * 256 + c];
        s1 += v * a[c];
        s2 += v * a[256 + c];
    }
#pragma unroll
    for (int off = 32; off; off >>= 1) {
        s1 += __shfl_down(s1, off);
        s2 += __shfl_down(s2, off);
    }
    if (lane == 0) {
        Wh1[row] = s1;
        Wh2[row] = s2;
        unsigned u = __float_as_uint(s2);
        unsigned key = (u & 0x80000000u) ? ~u : (u | 0x80000000u);
        atomicMax(maxenc, key);
    }
}

// WhT[n][k] bf16 from Wh[k][n] fp32, 64x64 LDS tile
__global__ __launch_bounds__(256) void k_transpose(const float* __restrict__ Wh, short* __restrict__ WhT) {
    __shared__ short sT[64 * 72];
    int bm = blockIdx.x, bn = blockIdx.y;
    int t = threadIdx.x;
#pragma unroll
    for (int i = 0; i < 4; i++) {
        int idx = i * 256 + t;
        int r = idx >> 4, c4 = (idx & 15) * 4;
        float4v v = *(const float4v*)&Wh[(size_t)(64 * bm + r) * 256 + 64 * bn + c4];
#pragma unroll
        for (int j = 0; j < 4; j++) sT[(c4 + j) * 72 + r] = f2bf(v[j]);
    }
    __syncthreads();
    int c = t >> 2, ro = (t & 3) * 16;
#pragma unroll
    for (int hh = 0; hh < 2; hh++) {
        short8v v = *(const short8v*)&sT[c * 72 + ro + 8 * hh];
        *(short8v*)&WhT[(size_t)(64 * bn + c) * 8192 + 64 * bm + ro + 8 * hh] = v;
    }
}

// Fused masked-softmax GEMM. Grid (128, S). Block 512 thr / 8 waves = 2 mt x 4 ng.
// M=64, N=256, K-slice Ksub. P computed IN REGISTERS in MFMA A-frag layout (no sA).
// B double-buffered in LDS via global_load_lds DMA (XOR-swizzled rows, r7-proven):
// DMA for chunk ch+1 issues at the BOTTOM of iter ch -> a full iteration in flight
// before the single per-chunk barrier drains it. No staged VGPRs -> no spills.
__global__ __launch_bounds__(512, 2) void k_gat(const float* __restrict__ adj,
                                                const short* __restrict__ WhT,
                                                const float* __restrict__ Wh1, const float* __restrict__ Wh2,
                                                const unsigned* __restrict__ maxenc,
                                                float* __restrict__ Cpart, float* __restrict__ Lpart,
                                                int Ksub) {
    __shared__ short sB[2][256 * 64];   // 2 x 32 KB, unpadded, chunk-XOR swizzled
    int bm = blockIdx.x;
    int sidx = blockIdx.y;
    int kb = sidx * Ksub;
    int t = threadIdx.x;
    int lane = t & 63, l16 = lane & 15, quad = lane >> 4;
    int w = t >> 6;                  // 0..7
    int ng = w & 3;                  // n-group: cols ng*64..+63
    int mt = w >> 2;                 // m-tile: rows bm*64 + mt*32..+31
    int m0 = bm * 64 + mt * 32;
    int n0 = ng * 64;

    // decode global max(Wh2)
    unsigned key = maxenc[0];
    unsigned uu = (key & 0x80000000u) ? (key & 0x7fffffffu) : ~key;
    float maxw2 = __uint_as_float(uu);

    float wh1r[2], ci[2];
#pragma unroll
    for (int rr = 0; rr < 2; rr++) {
        wh1r[rr] = Wh1[m0 + rr * 16 + l16];
        float sup = wh1r[rr] + maxw2;
        ci[rr] = fmaxf(sup, 0.2f * sup);
    }

    const float* adjp0 = &adj[(size_t)(m0 + l16) * 8192 + kb + quad * 8];
    const float* adjp1 = adjp0 + (size_t)16 * 8192;
    const float* w2p   = &Wh2[kb + quad * 8];

    // DMA staging (r7-proven): chunk slot s = i*512 + t (i=0..3); LDS 16B-chunk = s;
    // row n = s>>3 = i*64 + (t>>3); src chunk = (s&7)^(n&7) — constant across i.
    int schunk = (t & 7) ^ ((t >> 3) & 7);
    const short* gb0 = &WhT[(size_t)(t >> 3) * 8192 + kb + schunk * 8];

    float4v acc[2][4];
#pragma unroll
    for (int rr = 0; rr < 2; rr++)
#pragma unroll
        for (int c = 0; c < 4; c++)
#pragma unroll
            for (int j = 0; j < 4; j++) acc[rr][c][j] = 0.f;
    float lsum0 = 0.f, lsum1 = 0.f;

    // stage chunk 0 into buffer 0
#pragma unroll
    for (int i = 0; i < 4; i++) {
        __builtin_amdgcn_global_load_lds(
            (const __attribute__((address_space(1))) void*)(gb0 + (size_t)i * 64 * 8192),
            (__attribute__((address_space(3))) void*)(&sB[0][(i * 512 + t) * 8]),
            16, 0, 0);
    }

    int nch = Ksub >> 6;
    for (int ch = 0; ch < nch; ch++) {
        int cur = ch & 1;
        __syncthreads();   // drains DMA(ch) [one full iter in flight] + adj loads

        // ---- P + MFMA for the two 32-wide k halves of this chunk
#pragma unroll
        for (int kk = 0; kk < 2; kk++) {
            int ko = ch * 64 + kk * 32;
            float4v a0a = *(const float4v*)(adjp0 + ko);
            float4v a0b = *(const float4v*)(adjp0 + ko + 4);
            float4v a1a = *(const float4v*)(adjp1 + ko);
            float4v a1b = *(const float4v*)(adjp1 + ko + 4);
            float4v w2a = *(const float4v*)(w2p + ko);
            float4v w2b = *(const float4v*)(w2p + ko + 4);
            short8v af0, af1;
#pragma unroll
            for (int j = 0; j < 8; j++) {
                float w2v = (j < 4) ? w2a[j] : w2b[j - 4];
                float aj0 = (j < 4) ? a0a[j] : a0b[j - 4];
                float aj1 = (j < 4) ? a1a[j] : a1b[j - 4];
                float s0 = wh1r[0] + w2v;
                float s1 = wh1r[1] + w2v;
                float f0 = fmaxf(s0, 0.2f * s0);
                float f1 = fmaxf(s1, 0.2f * s1);
                float p0 = __expf(f0 - ci[0]) * aj0;   // adj is exactly 0.0/1.0
                float p1 = __expf(f1 - ci[1]) * aj1;
                lsum0 += p0;
                lsum1 += p1;
                af0[j] = f2bf(p0);
                af1[j] = f2bf(p1);
            }
#pragma unroll
            for (int c = 0; c < 4; c++) {
                int n = n0 + c * 16 + l16;
                int chx = (kk * 4 + quad) ^ (n & 7);
                short8v bf = *(const short8v*)&sB[cur][n * 64 + chx * 8];
                acc[0][c] = __builtin_amdgcn_mfma_f32_16x16x32_bf16(af0, bf, acc[0][c], 0, 0, 0);
                acc[1][c] = __builtin_amdgcn_mfma_f32_16x16x32_bf16(af1, bf, acc[1][c], 0, 0, 0);
            }
        }

        // ---- issue next chunk's DMA into the other buffer (drains at next barrier;
        //      all waves finished reading that buffer before this point only after the
        //      barrier — but buffer cur^1 was last read in iter ch-1, and every wave
        //      passed barrier(ch) since, so the write is safe)
        if (ch + 1 < nch) {
            int nxt = cur ^ 1;
#pragma unroll
            for (int i = 0; i < 4; i++) {
                __builtin_amdgcn_global_load_lds(
                    (const __attribute__((address_space(1))) void*)(gb0 + (size_t)i * 64 * 8192 + (ch + 1) * 64),
                    (__attribute__((address_space(3))) void*)(&sB[nxt][(i * 512 + t) * 8]),
                    16, 0, 0);
            }
        }
    }

    // row sums: reduce across the 4 quads
    lsum0 += __shfl_xor(lsum0, 16);
    lsum0 += __shfl_xor(lsum0, 32);
    lsum1 += __shfl_xor(lsum1, 16);
    lsum1 += __shfl_xor(lsum1, 32);
    if (ng == 0 && quad == 0) {
        Lpart[(size_t)sidx * NN + m0 + l16]      = lsum0;
        Lpart[(size_t)sidx * NN + m0 + 16 + l16] = lsum1;
    }

    // C/D layout: col = l16, row(local) = quad*4 + j
#pragma unroll
    for (int rr = 0; rr < 2; rr++)
#pragma unroll
        for (int c = 0; c < 4; c++)
#pragma unroll
            for (int j = 0; j < 4; j++) {
                int row = m0 + rr * 16 + quad * 4 + j;
                int col = n0 + c * 16 + l16;
                Cpart[((size_t)sidx * NN + row) * 256 + col] = acc[rr][c][j];
            }
}

// out = elu( (sum_s Cpart[s]) / (sum_s Lpart[s]) )
__global__ __launch_bounds__(256) void k_final(const float* __restrict__ Cpart, const float* __restrict__ Lpart,
                                               float* __restrict__ out, int S) {
    int idx = blockIdx.x * 256 + threadIdx.x;     // one float4 per thread; 2048 blocks
    int row = idx >> 6;
    int c4 = (idx & 63) * 4;
    float4v sum;
    sum[0] = sum[1] = sum[2] = sum[3] = 0.f;
    float l = 0.f;
    for (int s = 0; s < S; s++) {
        float4v v = *(const float4v*)&Cpart[((size_t)s * NN + row) * 256 + c4];
#pragma unroll
        for (int j = 0; j < 4; j++) sum[j] += v[j];
        l += Lpart[(size_t)s * NN + row];
    }
    float inv = 1.0f / fmaxf(l, 1e-30f);
    float4v o;
#pragma unroll
    for (int j = 0; j < 4; j++) {
        float x = sum[j] * inv;
        o[j] = (x > 0.f) ? x : (__expf(x) - 1.f);
    }
    *(float4v*)&out[(size_t)row * 256 + c4] = o;
}

extern "C" void kernel_launch(void* const* d_in, const int* in_sizes, int n_in,
                              void* d_out, int out_size, void* d_ws, size_t ws_size,
                              hipStream_t stream) {
    const float* h   = (const float*)d_in[0];
    const float* adj = (const float*)d_in[1];
    const float* W   = (const float*)d_in[2];
    const float* a   = (const float*)d_in[3];
    float* out = (float*)d_out;

    int S = 4;
    if ((size_t)(12 * 1024 * 1024) + (size_t)S * 8 * 1024 * 1024 + (2 << 20) > ws_size) S = 2;
    int Ksub = NN / S;

    // ws layout (~45 MB at S=4):
    //  [0, 8MB)        Wh (fp32)
    //  [8MB, 12MB)     WhT (bf16)
    //  [12MB, 12+S*8)  Cpart (fp32, S slices)
    //  tail: WT 128KB | Wh1 32KB | Wh2 32KB | Lpart S*32KB | maxenc
    char* ws = (char*)d_ws;
    float*    Wh     = (float*)(ws);
    short*    WhT    = (short*)(ws + 8388608);
    float*    Cpart  = (float*)(ws + 12582912);
    char*     tail   = ws + 12582912 + (size_t)S * 8388608;
    short*    WT     = (short*)(tail);
    float*    Wh1    = (float*)(tail + 131072);
    float*    Wh2    = (float*)(tail + 163840);
    float*    Lpart  = (float*)(tail + 196608);
    unsigned* maxenc = (unsigned*)(tail + 196608 + S * 32768);

    hipMemsetAsync(maxenc, 0, sizeof(unsigned), stream);

    k_wt<<<256, 256, 0, stream>>>(W, WT);
    k_gemm1<<<dim3(128, 4), 256, 0, stream>>>(h, WT, Wh);
    k_rowstats<<<2048, 256, 0, stream>>>(Wh, a, Wh1, Wh2, maxenc);
    k_transpose<<<dim3(128, 4), 256, 0, stream>>>(Wh, WhT);
    k_gat<<<dim3(128, S), 512, 0, stream>>>(adj, WhT, Wh1, Wh2, maxenc, Cpart, Lpart, Ksub);
    k_final<<<2048, 256, 0, stream>>>(Cpart, Lpart, out, S);
}